// Round 1
// baseline (342.961 us; speedup 1.0000x reference)
//
#include <hip/hip_runtime.h>
#include <math.h>

#define T_LEN 4096
#define C_CH 64
#define B_N 64
#define NBINS 2049   // T/2 + 1
#define K2 6         // 2*TOP_K
#define TOPK 3
#define THRESH_V 0.2f

// ---------------- K0: transpose x[B,T,C] -> xt[B,C,T] ----------------
__global__ void transpose_kernel(const float* __restrict__ x, float* __restrict__ xt) {
    __shared__ float tile[64][65];
    const int b = blockIdx.y;
    const int t0 = blockIdx.x * 64;
    const int lane = threadIdx.x & 63;
    const int w = threadIdx.x >> 6;  // 0..3
    const float* xb = x + (size_t)b * T_LEN * C_CH;
#pragma unroll
    for (int i = 0; i < 16; ++i) {
        int r = w * 16 + i;
        tile[r][lane] = xb[(size_t)(t0 + r) * C_CH + lane];
    }
    __syncthreads();
    float* xtb = xt + (size_t)b * C_CH * T_LEN;
#pragma unroll
    for (int i = 0; i < 16; ++i) {
        int c = w * 16 + i;
        xtb[(size_t)c * T_LEN + t0 + lane] = tile[lane][c];
    }
}

// ---------------- K1: per (b, channel-pair) 4096-pt complex FFT + |rfft| accumulate ----
template <bool USE_XT>
__global__ void fft_amp_kernel(const float* __restrict__ src, float* __restrict__ amps) {
    __shared__ float2 Z[T_LEN];  // 32 KB
    const int pair = blockIdx.x;   // 0..31
    const int b = blockIdx.y;
    const int tid = threadIdx.x;
    const int c0 = pair * 2;

    // load (two real channels packed as complex) with bit-reversal for DIT
    for (int t = tid; t < T_LEN; t += 256) {
        float a, bb;
        if (USE_XT) {
            const float* base = src + ((size_t)b * C_CH + c0) * T_LEN;
            a = base[t];
            bb = base[T_LEN + t];
        } else {
            const float2 v = *(const float2*)(src + ((size_t)b * T_LEN + t) * C_CH + c0);
            a = v.x;
            bb = v.y;
        }
        int rev = (int)(__brev((unsigned)t) >> 20);  // 12-bit reverse
        Z[rev] = make_float2(a, bb);
    }
    __syncthreads();

    // radix-2 DIT, forward (exp(-2pi i k t / N))
    for (int m = 1; m < T_LEN; m <<= 1) {
        const float angs = -3.14159265358979323846f / (float)m;
        for (int idx = tid; idx < T_LEN / 2; idx += 256) {
            int j = idx & (m - 1);
            int i0 = ((idx & ~(m - 1)) << 1) | j;
            int i1 = i0 + m;
            float s, c;
            sincosf(angs * (float)j, &s, &c);
            float2 u = Z[i0];
            float2 v = Z[i1];
            float tr = v.x * c - v.y * s;
            float ti = v.x * s + v.y * c;
            Z[i0] = make_float2(u.x + tr, u.y + ti);
            Z[i1] = make_float2(u.x - tr, u.y - ti);
        }
        __syncthreads();
    }

    // Hermitian unpack of the two real spectra; accumulate |A_k| + |B_k|
    for (int k = tid; k < NBINS; k += 256) {
        float2 zk = Z[k];
        float2 zm = Z[(T_LEN - k) & (T_LEN - 1)];
        float ax = 0.5f * (zk.x + zm.x);
        float ay = 0.5f * (zk.y - zm.y);
        float bx = 0.5f * (zk.y + zm.y);
        float by = -0.5f * (zk.x - zm.x);
        float amp = sqrtf(ax * ax + ay * ay) + sqrtf(bx * bx + by * by);
        atomicAdd(&amps[(size_t)b * NBINS + k], amp);
    }
}

// ---------------- K2: top-6 bins per batch (lax.top_k tie semantics) ----------------
__global__ void topk_kernel(const float* __restrict__ amps, int* __restrict__ p_int,
                            int* __restrict__ preval) {
    __shared__ float vals[NBINS];
    __shared__ float sval[256];
    __shared__ int sidx[256];
    __shared__ int sel[K2];
    const int b = blockIdx.x;
    const int tid = threadIdx.x;
    for (int k = tid; k < NBINS; k += 256) vals[k] = amps[(size_t)b * NBINS + k];
    __syncthreads();
    for (int pass = 0; pass < K2; ++pass) {
        float bv = -INFINITY;
        int bi = NBINS;
        for (int k = tid; k < NBINS; k += 256) {
            float v = vals[k];
            if (v > bv || (v == bv && k < bi)) { bv = v; bi = k; }
        }
        sval[tid] = bv;
        sidx[tid] = bi;
        __syncthreads();
        for (int off = 128; off > 0; off >>= 1) {
            if (tid < off) {
                float ov = sval[tid + off];
                int oi = sidx[tid + off];
                if (ov > sval[tid] || (ov == sval[tid] && oi < sidx[tid])) {
                    sval[tid] = ov;
                    sidx[tid] = oi;
                }
            }
            __syncthreads();
        }
        if (tid == 0) {
            sel[pass] = sidx[0];
            vals[sidx[0]] = -INFINITY;
        }
        __syncthreads();
    }
    if (tid < K2) {
        int idx = sel[tid];
        float pf = (float)T_LEN / (float)(idx + 1);
        int ir = (pf >= 2.0f) && (pf <= (float)(T_LEN / 2));
        float pff = floorf(pf);
        int iri = (pff >= 2.0f) && (pff <= (float)(T_LEN / 2));
        int pi = (int)pff;
        pi = pi < 2 ? 2 : (pi > T_LEN / 2 ? T_LEN / 2 : pi);
        p_int[b * K2 + tid] = pi;
        preval[b * K2 + tid] = ir && iri;
    }
}

// ---------------- K3: autocorrelation score per (b, candidate) ----------------
__device__ __forceinline__ void block_scan_4096(float* a, float* tsum, int tid) {
    // in-place inclusive prefix sum over 4096 LDS floats; 16 contiguous per thread
    float loc[16];
    const int base = tid * 16;
    float s = 0.f;
#pragma unroll
    for (int i = 0; i < 16; ++i) {
        s += a[base + i];
        loc[i] = s;
    }
    tsum[tid] = s;
    __syncthreads();
    for (int off = 1; off < 256; off <<= 1) {
        float v = (tid >= off) ? tsum[tid - off] : 0.f;
        __syncthreads();
        tsum[tid] += v;
        __syncthreads();
    }
    float offs = tsum[tid] - s;  // exclusive offset for this thread's chunk
#pragma unroll
    for (int i = 0; i < 16; ++i) a[base + i] = offs + loc[i];
    __syncthreads();
}

__global__ void autocorr_kernel(const float* __restrict__ x, const int* __restrict__ p_int,
                                float* __restrict__ scores) {
    __shared__ float r_s[T_LEN];
    __shared__ float q_s[T_LEN];
    __shared__ float tsum[256];
    const int cand = blockIdx.x;  // 0..5
    const int b = blockIdx.y;
    const int tid = threadIdx.x;
    const int p = p_int[b * K2 + cand];
    const float* xb = x + (size_t)b * T_LEN * C_CH;

    for (int t = tid; t < T_LEN; t += 256) {
        const float4* row = (const float4*)(xb + (size_t)t * C_CH);
        float q = 0.f, r = 0.f;
        if (t + p < T_LEN) {
            const float4* row2 = (const float4*)(xb + (size_t)(t + p) * C_CH);
#pragma unroll
            for (int i = 0; i < 16; ++i) {
                float4 a = row[i], c = row2[i];
                r += a.x * c.x + a.y * c.y + a.z * c.z + a.w * c.w;
                q += a.x * a.x + a.y * a.y + a.z * a.z + a.w * a.w;
            }
        } else {
#pragma unroll
            for (int i = 0; i < 16; ++i) {
                float4 a = row[i];
                q += a.x * a.x + a.y * a.y + a.z * a.z + a.w * a.w;
            }
        }
        r_s[t] = r;
        q_s[t] = q;
    }
    __syncthreads();

    block_scan_4096(r_s, tsum, tid);
    block_scan_4096(q_s, tsum, tid);

    // segment cosines: CR[e] = (e==0) ? 0 : r_s[e-1]
    const int nper = T_LEN / p;
    float part = 0.f;
    for (int i = tid; i < nper - 1; i += 256) {
        int s0 = i * p;
        int e = s0 + p;
        int e2 = e + p;
        float crs = s0 ? r_s[s0 - 1] : 0.f;
        float dots = r_s[e - 1] - crs;
        float cqs = s0 ? q_s[s0 - 1] : 0.f;
        float qa = q_s[e - 1] - cqs;
        float qb = q_s[e2 - 1] - q_s[e - 1];
        float na = sqrtf(fmaxf(qa, 0.f));
        float nb = sqrtf(fmaxf(qb, 0.f));
        part += dots / fmaxf(na * nb, 1e-8f);
    }
    tsum[tid] = part;
    __syncthreads();
    for (int off = 128; off > 0; off >>= 1) {
        if (tid < off) tsum[tid] += tsum[tid + off];
        __syncthreads();
    }
    if (tid == 0) scores[b * K2 + cand] = tsum[0] / (float)(nper - 1);
}

// ---------------- K4: final selection + fallback fill ----------------
__global__ void select_kernel(const int* __restrict__ p_int, const int* __restrict__ preval,
                              const float* __restrict__ scores, float* __restrict__ out) {
    const int b = threadIdx.x;
    if (b >= B_N) return;
    int sel[TOPK];
    int cnt = 0;
    for (int j = 0; j < K2; ++j) {
        if (preval[b * K2 + j] && scores[b * K2 + j] > THRESH_V) {
            if (cnt < TOPK) sel[cnt] = p_int[b * K2 + j];
            cnt++;
        }
    }
    if (cnt > TOPK) cnt = TOPK;
    int add[4];
    int nadd = 0;
    int cms[4] = {T_LEN / 4, T_LEN / 3, T_LEN / 2, (int)((float)T_LEN / 1.5f)};
    for (int i = 0; i < 4; ++i)
        if (cms[i] >= 2 && cms[i] <= T_LEN / 2) add[nadd++] = cms[i];
    for (int j = 0; j < TOPK; ++j) {
        float pv, wv;
        if (j < cnt) {
            pv = (float)sel[j];
            wv = 1.0f;
        } else {
            int a = j - cnt;
            if (a > nadd - 1) a = nadd - 1;
            pv = (float)add[a];
            wv = 0.5f;
        }
        out[b * TOPK + j] = pv;
        out[B_N * TOPK + b * TOPK + j] = wv;
    }
}

extern "C" void kernel_launch(void* const* d_in, const int* in_sizes, int n_in,
                              void* d_out, int out_size, void* d_ws, size_t ws_size,
                              hipStream_t stream) {
    const float* x = (const float*)d_in[0];
    float* out = (float*)d_out;
    char* ws = (char*)d_ws;

    const size_t xt_bytes = (size_t)B_N * C_CH * T_LEN * sizeof(float);     // 64 MB
    const size_t amps_bytes = (size_t)B_N * NBINS * sizeof(float);          // ~0.5 MB
    const size_t int_bytes = (size_t)B_N * K2 * sizeof(int);
    const size_t small_bytes = amps_bytes + 2 * int_bytes + (size_t)B_N * K2 * sizeof(float);

    const bool use_xt = ws_size >= xt_bytes + small_bytes;

    float* xt = (float*)ws;
    char* p2 = ws + (use_xt ? xt_bytes : 0);
    float* amps = (float*)p2;
    int* p_int = (int*)(p2 + amps_bytes);
    int* preval = (int*)(p2 + amps_bytes + int_bytes);
    float* scores = (float*)(p2 + amps_bytes + 2 * int_bytes);

    hipMemsetAsync(amps, 0, amps_bytes, stream);

    if (use_xt) {
        transpose_kernel<<<dim3(T_LEN / 64, B_N), 256, 0, stream>>>(x, xt);
        fft_amp_kernel<true><<<dim3(C_CH / 2, B_N), 256, 0, stream>>>(xt, amps);
    } else {
        fft_amp_kernel<false><<<dim3(C_CH / 2, B_N), 256, 0, stream>>>(x, amps);
    }
    topk_kernel<<<B_N, 256, 0, stream>>>(amps, p_int, preval);
    autocorr_kernel<<<dim3(K2, B_N), 256, 0, stream>>>(x, p_int, scores);
    select_kernel<<<1, 64, 0, stream>>>(p_int, preval, scores, out);
}

// Round 2
// 253.643 us; speedup vs baseline: 1.3521x; 1.3521x over previous
//
#include <hip/hip_runtime.h>
#include <math.h>

#define T_LEN 4096
#define C_CH 64
#define B_N 64
#define NBINS 2049   // T/2 + 1
#define K2 6         // 2*TOP_K
#define TOPK 3
#define THRESH_V 0.2f

// ---------------- K1: per (b, channel-pair) 4096-pt complex FFT + |rfft| accumulate ----
__global__ void fft_amp_kernel(const float* __restrict__ src, float* __restrict__ amps) {
    __shared__ float2 Z[T_LEN];  // 32 KB
    const int pair = blockIdx.x;   // 0..31
    const int b = blockIdx.y;
    const int tid = threadIdx.x;
    const int c0 = pair * 2;

    // load (two real channels packed as complex) with bit-reversal for DIT
    for (int t = tid; t < T_LEN; t += 256) {
        const float2 v = *(const float2*)(src + ((size_t)b * T_LEN + t) * C_CH + c0);
        int rev = (int)(__brev((unsigned)t) >> 20);  // 12-bit reverse
        Z[rev] = v;
    }
    __syncthreads();

    // radix-2 DIT, forward (exp(-2pi i k t / N))
    for (int m = 1; m < T_LEN; m <<= 1) {
        const float angs = -3.14159265358979323846f / (float)m;
        for (int idx = tid; idx < T_LEN / 2; idx += 256) {
            int j = idx & (m - 1);
            int i0 = ((idx & ~(m - 1)) << 1) | j;
            int i1 = i0 + m;
            float s, c;
            __sincosf(angs * (float)j, &s, &c);
            float2 u = Z[i0];
            float2 v = Z[i1];
            float tr = v.x * c - v.y * s;
            float ti = v.x * s + v.y * c;
            Z[i0] = make_float2(u.x + tr, u.y + ti);
            Z[i1] = make_float2(u.x - tr, u.y - ti);
        }
        __syncthreads();
    }

    // Hermitian unpack of the two real spectra; accumulate |A_k| + |B_k|
    for (int k = tid; k < NBINS; k += 256) {
        float2 zk = Z[k];
        float2 zm = Z[(T_LEN - k) & (T_LEN - 1)];
        float ax = 0.5f * (zk.x + zm.x);
        float ay = 0.5f * (zk.y - zm.y);
        float bx = 0.5f * (zk.y + zm.y);
        float by = -0.5f * (zk.x - zm.x);
        float amp = sqrtf(ax * ax + ay * ay) + sqrtf(bx * bx + by * by);
        atomicAdd(&amps[(size_t)b * NBINS + k], amp);
    }
}

// ---------------- K2: top-6 bins per batch (lax.top_k tie semantics) ----------------
__global__ void topk_kernel(const float* __restrict__ amps, int* __restrict__ p_int,
                            int* __restrict__ preval) {
    __shared__ float vals[NBINS];
    __shared__ float sval[256];
    __shared__ int sidx[256];
    __shared__ int sel[K2];
    const int b = blockIdx.x;
    const int tid = threadIdx.x;
    for (int k = tid; k < NBINS; k += 256) vals[k] = amps[(size_t)b * NBINS + k];
    __syncthreads();
    for (int pass = 0; pass < K2; ++pass) {
        float bv = -INFINITY;
        int bi = NBINS;
        for (int k = tid; k < NBINS; k += 256) {
            float v = vals[k];
            if (v > bv || (v == bv && k < bi)) { bv = v; bi = k; }
        }
        sval[tid] = bv;
        sidx[tid] = bi;
        __syncthreads();
        for (int off = 128; off > 0; off >>= 1) {
            if (tid < off) {
                float ov = sval[tid + off];
                int oi = sidx[tid + off];
                if (ov > sval[tid] || (ov == sval[tid] && oi < sidx[tid])) {
                    sval[tid] = ov;
                    sidx[tid] = oi;
                }
            }
            __syncthreads();
        }
        if (tid == 0) {
            sel[pass] = sidx[0];
            vals[sidx[0]] = -INFINITY;
        }
        __syncthreads();
    }
    if (tid < K2) {
        int idx = sel[tid];
        float pf = (float)T_LEN / (float)(idx + 1);
        int ir = (pf >= 2.0f) && (pf <= (float)(T_LEN / 2));
        float pff = floorf(pf);
        int iri = (pff >= 2.0f) && (pff <= (float)(T_LEN / 2));
        int pi = (int)pff;
        pi = pi < 2 ? 2 : (pi > T_LEN / 2 ? T_LEN / 2 : pi);
        p_int[b * K2 + tid] = pi;
        preval[b * K2 + tid] = ir && iri;
    }
}

// ---------------- K3a: r[t],q[t] producer — 1024 blocks, coalesced row bursts ----------
__global__ void rq_kernel(const float* __restrict__ x, const int* __restrict__ p_int,
                          float* __restrict__ r_ws, float* __restrict__ q_ws) {
    const int b = blockIdx.y;
    const int t0 = blockIdx.x * 256;
    const int tid = threadIdx.x;
    const int lane16 = tid & 15;   // position within one 256 B row
    const int g = tid >> 4;        // row group 0..15
    __shared__ int ps[K2];
    if (tid < K2) ps[tid] = p_int[b * K2 + tid];
    __syncthreads();
    const float* xb = x + (size_t)b * T_LEN * C_CH;

    for (int k = 0; k < 16; ++k) {
        const int t = t0 + k * 16 + g;   // wave covers 4 contiguous rows per load
        const float4 a = ((const float4*)(xb + (size_t)t * C_CH))[lane16];
        float q = a.x * a.x + a.y * a.y + a.z * a.z + a.w * a.w;
        q += __shfl_xor(q, 1);
        q += __shfl_xor(q, 2);
        q += __shfl_xor(q, 4);
        q += __shfl_xor(q, 8);
        if (lane16 == 0) q_ws[(size_t)b * T_LEN + t] = q;
#pragma unroll
        for (int c = 0; c < K2; ++c) {
            const int p = ps[c];
            float r = 0.f;
            if (t + p < T_LEN) {   // uniform across the 16-lane group
                const float4 bv = ((const float4*)(xb + (size_t)(t + p) * C_CH))[lane16];
                r = a.x * bv.x + a.y * bv.y + a.z * bv.z + a.w * bv.w;
            }
            r += __shfl_xor(r, 1);
            r += __shfl_xor(r, 2);
            r += __shfl_xor(r, 4);
            r += __shfl_xor(r, 8);
            if (lane16 == 0) r_ws[((size_t)b * K2 + c) * T_LEN + t] = r;
        }
    }
}

// ---------------- shared scan helper ----------------
__device__ __forceinline__ void block_scan_4096(float* a, float* tsum, int tid) {
    // in-place inclusive prefix sum over 4096 LDS floats; 16 contiguous per thread
    float loc[16];
    const int base = tid * 16;
    float s = 0.f;
#pragma unroll
    for (int i = 0; i < 16; ++i) {
        s += a[base + i];
        loc[i] = s;
    }
    tsum[tid] = s;
    __syncthreads();
    for (int off = 1; off < 256; off <<= 1) {
        float v = (tid >= off) ? tsum[tid - off] : 0.f;
        __syncthreads();
        tsum[tid] += v;
        __syncthreads();
    }
    float offs = tsum[tid] - s;  // exclusive offset for this thread's chunk
#pragma unroll
    for (int i = 0; i < 16; ++i) a[base + i] = offs + loc[i];
    __syncthreads();
}

// ---------------- K3b: scan + segment cosines from precomputed r,q ----------------
__global__ void score_kernel(const float* __restrict__ r_ws, const float* __restrict__ q_ws,
                             const int* __restrict__ p_int, float* __restrict__ scores) {
    __shared__ float r_s[T_LEN];
    __shared__ float q_s[T_LEN];
    __shared__ float tsum[256];
    const int cand = blockIdx.x;
    const int b = blockIdx.y;
    const int tid = threadIdx.x;
    const int p = p_int[b * K2 + cand];
    const float4* rsrc = (const float4*)(r_ws + ((size_t)b * K2 + cand) * T_LEN);
    const float4* qsrc = (const float4*)(q_ws + (size_t)b * T_LEN);
    for (int i = tid; i < T_LEN / 4; i += 256) {
        ((float4*)r_s)[i] = rsrc[i];
        ((float4*)q_s)[i] = qsrc[i];
    }
    __syncthreads();

    block_scan_4096(r_s, tsum, tid);
    block_scan_4096(q_s, tsum, tid);

    const int nper = T_LEN / p;
    float part = 0.f;
    for (int i = tid; i < nper - 1; i += 256) {
        int s0 = i * p;
        int e = s0 + p;
        int e2 = e + p;
        float crs = s0 ? r_s[s0 - 1] : 0.f;
        float dots = r_s[e - 1] - crs;
        float cqs = s0 ? q_s[s0 - 1] : 0.f;
        float qa = q_s[e - 1] - cqs;
        float qb = q_s[e2 - 1] - q_s[e - 1];
        float na = sqrtf(fmaxf(qa, 0.f));
        float nb = sqrtf(fmaxf(qb, 0.f));
        part += dots / fmaxf(na * nb, 1e-8f);
    }
    tsum[tid] = part;
    __syncthreads();
    for (int off = 128; off > 0; off >>= 1) {
        if (tid < off) tsum[tid] += tsum[tid + off];
        __syncthreads();
    }
    if (tid == 0) scores[b * K2 + cand] = tsum[0] / (float)(nper - 1);
}

// ---------------- fallback: original fused autocorr (used only if ws too small) -------
__global__ void autocorr_kernel(const float* __restrict__ x, const int* __restrict__ p_int,
                                float* __restrict__ scores) {
    __shared__ float r_s[T_LEN];
    __shared__ float q_s[T_LEN];
    __shared__ float tsum[256];
    const int cand = blockIdx.x;
    const int b = blockIdx.y;
    const int tid = threadIdx.x;
    const int p = p_int[b * K2 + cand];
    const float* xb = x + (size_t)b * T_LEN * C_CH;

    for (int t = tid; t < T_LEN; t += 256) {
        const float4* row = (const float4*)(xb + (size_t)t * C_CH);
        float q = 0.f, r = 0.f;
        if (t + p < T_LEN) {
            const float4* row2 = (const float4*)(xb + (size_t)(t + p) * C_CH);
#pragma unroll
            for (int i = 0; i < 16; ++i) {
                float4 a = row[i], c = row2[i];
                r += a.x * c.x + a.y * c.y + a.z * c.z + a.w * c.w;
                q += a.x * a.x + a.y * a.y + a.z * a.z + a.w * a.w;
            }
        } else {
#pragma unroll
            for (int i = 0; i < 16; ++i) {
                float4 a = row[i];
                q += a.x * a.x + a.y * a.y + a.z * a.z + a.w * a.w;
            }
        }
        r_s[t] = r;
        q_s[t] = q;
    }
    __syncthreads();
    block_scan_4096(r_s, tsum, tid);
    block_scan_4096(q_s, tsum, tid);
    const int nper = T_LEN / p;
    float part = 0.f;
    for (int i = tid; i < nper - 1; i += 256) {
        int s0 = i * p;
        int e = s0 + p;
        int e2 = e + p;
        float crs = s0 ? r_s[s0 - 1] : 0.f;
        float dots = r_s[e - 1] - crs;
        float cqs = s0 ? q_s[s0 - 1] : 0.f;
        float qa = q_s[e - 1] - cqs;
        float qb = q_s[e2 - 1] - q_s[e - 1];
        float na = sqrtf(fmaxf(qa, 0.f));
        float nb = sqrtf(fmaxf(qb, 0.f));
        part += dots / fmaxf(na * nb, 1e-8f);
    }
    tsum[tid] = part;
    __syncthreads();
    for (int off = 128; off > 0; off >>= 1) {
        if (tid < off) tsum[tid] += tsum[tid + off];
        __syncthreads();
    }
    if (tid == 0) scores[b * K2 + cand] = tsum[0] / (float)(nper - 1);
}

// ---------------- K4: final selection + fallback fill ----------------
__global__ void select_kernel(const int* __restrict__ p_int, const int* __restrict__ preval,
                              const float* __restrict__ scores, float* __restrict__ out) {
    const int b = threadIdx.x;
    if (b >= B_N) return;
    int sel[TOPK];
    int cnt = 0;
    for (int j = 0; j < K2; ++j) {
        if (preval[b * K2 + j] && scores[b * K2 + j] > THRESH_V) {
            if (cnt < TOPK) sel[cnt] = p_int[b * K2 + j];
            cnt++;
        }
    }
    if (cnt > TOPK) cnt = TOPK;
    int add[4];
    int nadd = 0;
    int cms[4] = {T_LEN / 4, T_LEN / 3, T_LEN / 2, (int)((float)T_LEN / 1.5f)};
    for (int i = 0; i < 4; ++i)
        if (cms[i] >= 2 && cms[i] <= T_LEN / 2) add[nadd++] = cms[i];
    for (int j = 0; j < TOPK; ++j) {
        float pv, wv;
        if (j < cnt) {
            pv = (float)sel[j];
            wv = 1.0f;
        } else {
            int a = j - cnt;
            if (a > nadd - 1) a = nadd - 1;
            pv = (float)add[a];
            wv = 0.5f;
        }
        out[b * TOPK + j] = pv;
        out[B_N * TOPK + b * TOPK + j] = wv;
    }
}

extern "C" void kernel_launch(void* const* d_in, const int* in_sizes, int n_in,
                              void* d_out, int out_size, void* d_ws, size_t ws_size,
                              hipStream_t stream) {
    const float* x = (const float*)d_in[0];
    float* out = (float*)d_out;
    char* ws = (char*)d_ws;

    const size_t amps_bytes = (size_t)B_N * NBINS * sizeof(float);          // ~0.5 MB
    const size_t r_bytes = (size_t)B_N * K2 * T_LEN * sizeof(float);        // 6.3 MB
    const size_t q_bytes = (size_t)B_N * T_LEN * sizeof(float);             // 1 MB
    const size_t int_bytes = (size_t)B_N * K2 * sizeof(int);
    const size_t score_bytes = (size_t)B_N * K2 * sizeof(float);

    float* amps = (float*)ws;
    float* r_ws = (float*)(ws + amps_bytes);
    float* q_ws = (float*)(ws + amps_bytes + r_bytes);
    char* p3 = ws + amps_bytes + r_bytes + q_bytes;
    const size_t need = amps_bytes + r_bytes + q_bytes + 2 * int_bytes + score_bytes;
    const bool split_path = ws_size >= need;
    if (!split_path) p3 = ws + amps_bytes;   // compact layout for fallback
    int* p_int = (int*)p3;
    int* preval = (int*)(p3 + int_bytes);
    float* scores = (float*)(p3 + 2 * int_bytes);

    hipMemsetAsync(amps, 0, amps_bytes, stream);

    fft_amp_kernel<<<dim3(C_CH / 2, B_N), 256, 0, stream>>>(x, amps);
    topk_kernel<<<B_N, 256, 0, stream>>>(amps, p_int, preval);
    if (split_path) {
        rq_kernel<<<dim3(T_LEN / 256, B_N), 256, 0, stream>>>(x, p_int, r_ws, q_ws);
        score_kernel<<<dim3(K2, B_N), 256, 0, stream>>>(r_ws, q_ws, p_int, scores);
    } else {
        autocorr_kernel<<<dim3(K2, B_N), 256, 0, stream>>>(x, p_int, scores);
    }
    select_kernel<<<1, 64, 0, stream>>>(p_int, preval, scores, out);
}

// Round 3
// 217.506 us; speedup vs baseline: 1.5768x; 1.1661x over previous
//
#include <hip/hip_runtime.h>
#include <math.h>

#define T_LEN 4096
#define C_CH 64
#define B_N 64
#define NBINS 2049   // T/2 + 1
#define K2 6         // 2*TOP_K
#define TOPK 3
#define THRESH_V 0.2f

// ---------------- complex helpers ----------------
__device__ __forceinline__ float2 cmul(float2 a, float2 b) {
    return make_float2(a.x * b.x - a.y * b.y, a.x * b.y + a.y * b.x);
}
__device__ __forceinline__ float2 cadd(float2 a, float2 b) { return make_float2(a.x + b.x, a.y + b.y); }
__device__ __forceinline__ float2 csub(float2 a, float2 b) { return make_float2(a.x - b.x, a.y - b.y); }

// 16-point forward DFT in registers (natural in, natural out), radix-2 DIT.
__device__ __forceinline__ void dft16(float2* v) {
    const float C2 = 0.70710678118654752f;
    const float C1 = 0.92387953251128676f;
    const float S1 = 0.38268343236508977f;
    const int br[16] = {0, 8, 4, 12, 2, 10, 6, 14, 1, 9, 5, 13, 3, 11, 7, 15};
    float2 a[16];
#pragma unroll
    for (int i = 0; i < 16; ++i) a[i] = v[br[i]];
    // m=1
#pragma unroll
    for (int g = 0; g < 16; g += 2) {
        float2 t = a[g + 1];
        a[g + 1] = csub(a[g], t);
        a[g] = cadd(a[g], t);
    }
    // m=2: W={1,-i}
#pragma unroll
    for (int g = 0; g < 16; g += 4) {
        {
            float2 t = a[g + 2];
            a[g + 2] = csub(a[g], t);
            a[g] = cadd(a[g], t);
        }
        {
            float2 t = make_float2(a[g + 3].y, -a[g + 3].x);  // -i * z
            a[g + 3] = csub(a[g + 1], t);
            a[g + 1] = cadd(a[g + 1], t);
        }
    }
    // m=4
    {
        const float2 W4[4] = {{1.f, 0.f}, {C2, -C2}, {0.f, -1.f}, {-C2, -C2}};
#pragma unroll
        for (int g = 0; g < 16; g += 8)
#pragma unroll
            for (int j = 0; j < 4; ++j) {
                float2 t = cmul(W4[j], a[g + 4 + j]);
                a[g + 4 + j] = csub(a[g + j], t);
                a[g + j] = cadd(a[g + j], t);
            }
    }
    // m=8
    {
        const float2 W8[8] = {{1.f, 0.f}, {C1, -S1}, {C2, -C2}, {S1, -C1},
                              {0.f, -1.f}, {-S1, -C1}, {-C2, -C2}, {-C1, -S1}};
#pragma unroll
        for (int j = 0; j < 8; ++j) {
            float2 t = cmul(W8[j], a[8 + j]);
            a[8 + j] = csub(a[j], t);
            a[j] = cadd(a[j], t);
        }
    }
#pragma unroll
    for (int i = 0; i < 16; ++i) v[i] = a[i];
}

// ---------------- K0: transpose x[B,T,C] -> xt[B,C,T]  +  bf16 copy xbf[B,T,C] ------
__global__ void transpose_cvt_kernel(const float* __restrict__ x, float* __restrict__ xt,
                                     unsigned short* __restrict__ xbf) {
    __shared__ float tile[64][65];
    const int b = blockIdx.y;
    const int t0 = blockIdx.x * 64;
    const int lane = threadIdx.x & 63;
    const int w = threadIdx.x >> 6;  // 0..3
    const float* xb = x + (size_t)b * T_LEN * C_CH;
    unsigned short* xbf_b = xbf + (size_t)b * T_LEN * C_CH;
#pragma unroll
    for (int i = 0; i < 16; ++i) {
        int r = w * 16 + i;
        float val = xb[(size_t)(t0 + r) * C_CH + lane];
        tile[r][lane] = val;
        unsigned int u = __float_as_uint(val);
        u += 0x8000u + ((u >> 16) & 1u);  // RNE to bf16
        xbf_b[(size_t)(t0 + r) * C_CH + lane] = (unsigned short)(u >> 16);
    }
    __syncthreads();
    float* xtb = xt + (size_t)b * C_CH * T_LEN;
#pragma unroll
    for (int i = 0; i < 16; ++i) {
        int c = w * 16 + i;
        xtb[(size_t)c * T_LEN + t0 + lane] = tile[lane][c];
    }
}

// standalone converter for the mid-tier ws fallback
__global__ void cvt_kernel(const float* __restrict__ x, unsigned short* __restrict__ xbf) {
    const int n4 = B_N * T_LEN * C_CH / 4;
    for (int i = blockIdx.x * 256 + threadIdx.x; i < n4; i += gridDim.x * 256) {
        float4 v = ((const float4*)x)[i];
        unsigned int u0 = __float_as_uint(v.x); u0 += 0x8000u + ((u0 >> 16) & 1u);
        unsigned int u1 = __float_as_uint(v.y); u1 += 0x8000u + ((u1 >> 16) & 1u);
        unsigned int u2 = __float_as_uint(v.z); u2 += 0x8000u + ((u2 >> 16) & 1u);
        unsigned int u3 = __float_as_uint(v.w); u3 += 0x8000u + ((u3 >> 16) & 1u);
        uint2 o;
        o.x = (u0 >> 16) | (u1 & 0xFFFF0000u);
        o.y = (u2 >> 16) | (u3 & 0xFFFF0000u);
        ((uint2*)xbf)[i] = o;
    }
}

// ---------------- K1: radix-16 4096-pt complex FFT + |rfft| accumulate ----------------
// XT=true: coalesced loads from xt[B,C,T]; XT=false: strided loads from x[B,T,C].
template <bool XT>
__global__ void fft_amp_kernel(const float* __restrict__ src, float* __restrict__ amps) {
    __shared__ float2 Z[T_LEN];  // 32 KB
    const int pair = blockIdx.x;  // 0..31
    const int b = blockIdx.y;
    const int tid = threadIdx.x;

    if (XT) {
        const float* r0 = src + ((size_t)b * C_CH + pair * 2) * T_LEN;
        const float* r1 = r0 + T_LEN;
        for (int t = tid; t < T_LEN; t += 256) Z[t] = make_float2(r0[t], r1[t]);
    } else {
        const int c0 = pair * 2;
        for (int t = tid; t < T_LEN; t += 256)
            Z[t] = *(const float2*)(src + ((size_t)b * T_LEN + t) * C_CH + c0);
    }
    __syncthreads();

    // ---- stage 0: n1 = tid; y_r[n1] = (DFT16 over n2)(r) * w4096^(n1 r) -> Z[256r + n1]
    {
        float2 v[16];
#pragma unroll
        for (int t = 0; t < 16; ++t) v[t] = Z[tid + 256 * t];
        dft16(v);
        float s, c;
        __sincosf(-(float)tid * 1.5339807878856412e-3f, &s, &c);  // -2pi/4096 * n1
        float2 w1 = make_float2(c, s), w = w1;
#pragma unroll
        for (int r = 1; r < 16; ++r) {
            v[r] = cmul(v[r], w);
            w = cmul(w, w1);
        }
#pragma unroll
        for (int r = 0; r < 16; ++r) Z[256 * r + tid] = v[r];  // same slots it read (mod-256 class)
    }
    __syncthreads();

    // ---- stage 1: r = tid>>4, mu = tid&15; DFT16 over nu -> rho; twiddle w256^(mu rho)
    {
        const int r = tid >> 4, mu = tid & 15;
        float2 v[16];
#pragma unroll
        for (int nu = 0; nu < 16; ++nu) v[nu] = Z[256 * r + mu + 16 * nu];
        dft16(v);
        float s, c;
        __sincosf(-(float)mu * 2.4543692606170259e-2f, &s, &c);  // -2pi/256 * mu
        float2 w1 = make_float2(c, s), w = w1;
#pragma unroll
        for (int rho = 1; rho < 16; ++rho) {
            v[rho] = cmul(v[rho], w);
            w = cmul(w, w1);
        }
        __syncthreads();  // write set differs from read set across threads
#pragma unroll
        for (int rho = 0; rho < 16; ++rho) Z[256 * r + 16 * mu + rho] = v[rho];
    }
    __syncthreads();

    // ---- stage 2: r = tid>>4, rho = tid&15; DFT16 over mu -> m'; in-place per-thread
    {
        const int r = tid >> 4, rho = tid & 15;
        float2 v[16];
#pragma unroll
        for (int mu = 0; mu < 16; ++mu) v[mu] = Z[256 * r + 16 * mu + rho];
        dft16(v);
#pragma unroll
        for (int mp = 0; mp < 16; ++mp) Z[256 * r + 16 * mp + rho] = v[mp];
    }
    __syncthreads();

    // ---- Hermitian unpack; X[k] stored at s(k) = 256*(k&15) + 16*(k>>8) + ((k>>4)&15)
    for (int k = tid; k < NBINS; k += 256) {
        int km = (T_LEN - k) & (T_LEN - 1);
        int sk = 256 * (k & 15) + 16 * (k >> 8) + ((k >> 4) & 15);
        int sm = 256 * (km & 15) + 16 * (km >> 8) + ((km >> 4) & 15);
        float2 zk = Z[sk];
        float2 zm = Z[sm];
        float ax = 0.5f * (zk.x + zm.x);
        float ay = 0.5f * (zk.y - zm.y);
        float bx = 0.5f * (zk.y + zm.y);
        float by = -0.5f * (zk.x - zm.x);
        float amp = sqrtf(ax * ax + ay * ay) + sqrtf(bx * bx + by * by);
        atomicAdd(&amps[(size_t)b * NBINS + k], amp);
    }
}

// ---------------- K2: top-6 bins per batch (lax.top_k tie semantics) ----------------
__global__ void topk_kernel(const float* __restrict__ amps, int* __restrict__ p_int,
                            int* __restrict__ preval) {
    __shared__ float vals[NBINS];
    __shared__ float sval[256];
    __shared__ int sidx[256];
    __shared__ int sel[K2];
    const int b = blockIdx.x;
    const int tid = threadIdx.x;
    for (int k = tid; k < NBINS; k += 256) vals[k] = amps[(size_t)b * NBINS + k];
    __syncthreads();
    for (int pass = 0; pass < K2; ++pass) {
        float bv = -INFINITY;
        int bi = NBINS;
        for (int k = tid; k < NBINS; k += 256) {
            float v = vals[k];
            if (v > bv || (v == bv && k < bi)) { bv = v; bi = k; }
        }
        sval[tid] = bv;
        sidx[tid] = bi;
        __syncthreads();
        for (int off = 128; off > 0; off >>= 1) {
            if (tid < off) {
                float ov = sval[tid + off];
                int oi = sidx[tid + off];
                if (ov > sval[tid] || (ov == sval[tid] && oi < sidx[tid])) {
                    sval[tid] = ov;
                    sidx[tid] = oi;
                }
            }
            __syncthreads();
        }
        if (tid == 0) {
            sel[pass] = sidx[0];
            vals[sidx[0]] = -INFINITY;
        }
        __syncthreads();
    }
    if (tid < K2) {
        int idx = sel[tid];
        float pf = (float)T_LEN / (float)(idx + 1);
        int ir = (pf >= 2.0f) && (pf <= (float)(T_LEN / 2));
        float pff = floorf(pf);
        int iri = (pff >= 2.0f) && (pff <= (float)(T_LEN / 2));
        int pi = (int)pff;
        pi = pi < 2 ? 2 : (pi > T_LEN / 2 ? T_LEN / 2 : pi);
        p_int[b * K2 + tid] = pi;
        preval[b * K2 + tid] = ir && iri;
    }
}

// ---------------- K3a: r[t],q[t] producer from bf16 copy ----------------
__global__ void rq_kernel(const unsigned short* __restrict__ xbf, const int* __restrict__ p_int,
                          float* __restrict__ r_ws, float* __restrict__ q_ws) {
    const int b = blockIdx.y;
    const int t0 = blockIdx.x * 256;
    const int tid = threadIdx.x;
    const int lane16 = tid & 15;  // position within one 128 B bf16 row
    const int g = tid >> 4;
    __shared__ int ps[K2];
    if (tid < K2) ps[tid] = p_int[b * K2 + tid];
    __syncthreads();
    const unsigned short* xb = xbf + (size_t)b * T_LEN * C_CH;

    for (int k = 0; k < 16; ++k) {
        const int t = t0 + k * 16 + g;
        const uint2 u = ((const uint2*)(xb + (size_t)t * C_CH))[lane16];
        float a0 = __uint_as_float(u.x << 16);
        float a1 = __uint_as_float(u.x & 0xFFFF0000u);
        float a2 = __uint_as_float(u.y << 16);
        float a3 = __uint_as_float(u.y & 0xFFFF0000u);
        float q = a0 * a0 + a1 * a1 + a2 * a2 + a3 * a3;
        q += __shfl_xor(q, 1);
        q += __shfl_xor(q, 2);
        q += __shfl_xor(q, 4);
        q += __shfl_xor(q, 8);
        if (lane16 == 0) q_ws[(size_t)b * T_LEN + t] = q;
#pragma unroll
        for (int c = 0; c < K2; ++c) {
            const int p = ps[c];
            float r = 0.f;
            if (t + p < T_LEN) {  // uniform across the 16-lane group
                const uint2 w = ((const uint2*)(xb + (size_t)(t + p) * C_CH))[lane16];
                float b0 = __uint_as_float(w.x << 16);
                float b1 = __uint_as_float(w.x & 0xFFFF0000u);
                float b2 = __uint_as_float(w.y << 16);
                float b3 = __uint_as_float(w.y & 0xFFFF0000u);
                r = a0 * b0 + a1 * b1 + a2 * b2 + a3 * b3;
            }
            r += __shfl_xor(r, 1);
            r += __shfl_xor(r, 2);
            r += __shfl_xor(r, 4);
            r += __shfl_xor(r, 8);
            if (lane16 == 0) r_ws[((size_t)b * K2 + c) * T_LEN + t] = r;
        }
    }
}

// ---------------- shared scan helper ----------------
__device__ __forceinline__ void block_scan_4096(float* a, float* tsum, int tid) {
    float loc[16];
    const int base = tid * 16;
    float s = 0.f;
#pragma unroll
    for (int i = 0; i < 16; ++i) {
        s += a[base + i];
        loc[i] = s;
    }
    tsum[tid] = s;
    __syncthreads();
    for (int off = 1; off < 256; off <<= 1) {
        float v = (tid >= off) ? tsum[tid - off] : 0.f;
        __syncthreads();
        tsum[tid] += v;
        __syncthreads();
    }
    float offs = tsum[tid] - s;
#pragma unroll
    for (int i = 0; i < 16; ++i) a[base + i] = offs + loc[i];
    __syncthreads();
}

// ---------------- K3b: scan + segment cosines ----------------
__global__ void score_kernel(const float* __restrict__ r_ws, const float* __restrict__ q_ws,
                             const int* __restrict__ p_int, float* __restrict__ scores) {
    __shared__ float r_s[T_LEN];
    __shared__ float q_s[T_LEN];
    __shared__ float tsum[256];
    const int cand = blockIdx.x;
    const int b = blockIdx.y;
    const int tid = threadIdx.x;
    const int p = p_int[b * K2 + cand];
    const float4* rsrc = (const float4*)(r_ws + ((size_t)b * K2 + cand) * T_LEN);
    const float4* qsrc = (const float4*)(q_ws + (size_t)b * T_LEN);
    for (int i = tid; i < T_LEN / 4; i += 256) {
        ((float4*)r_s)[i] = rsrc[i];
        ((float4*)q_s)[i] = qsrc[i];
    }
    __syncthreads();
    block_scan_4096(r_s, tsum, tid);
    block_scan_4096(q_s, tsum, tid);
    const int nper = T_LEN / p;
    float part = 0.f;
    for (int i = tid; i < nper - 1; i += 256) {
        int s0 = i * p;
        int e = s0 + p;
        int e2 = e + p;
        float crs = s0 ? r_s[s0 - 1] : 0.f;
        float dots = r_s[e - 1] - crs;
        float cqs = s0 ? q_s[s0 - 1] : 0.f;
        float qa = q_s[e - 1] - cqs;
        float qb = q_s[e2 - 1] - q_s[e - 1];
        float na = sqrtf(fmaxf(qa, 0.f));
        float nb = sqrtf(fmaxf(qb, 0.f));
        part += dots / fmaxf(na * nb, 1e-8f);
    }
    tsum[tid] = part;
    __syncthreads();
    for (int off = 128; off > 0; off >>= 1) {
        if (tid < off) tsum[tid] += tsum[tid + off];
        __syncthreads();
    }
    if (tid == 0) scores[b * K2 + cand] = tsum[0] / (float)(nper - 1);
}

// ---------------- fallback fused autocorr (tiny-ws path) ----------------
__global__ void autocorr_kernel(const float* __restrict__ x, const int* __restrict__ p_int,
                                float* __restrict__ scores) {
    __shared__ float r_s[T_LEN];
    __shared__ float q_s[T_LEN];
    __shared__ float tsum[256];
    const int cand = blockIdx.x;
    const int b = blockIdx.y;
    const int tid = threadIdx.x;
    const int p = p_int[b * K2 + cand];
    const float* xb = x + (size_t)b * T_LEN * C_CH;
    for (int t = tid; t < T_LEN; t += 256) {
        const float4* row = (const float4*)(xb + (size_t)t * C_CH);
        float q = 0.f, r = 0.f;
        if (t + p < T_LEN) {
            const float4* row2 = (const float4*)(xb + (size_t)(t + p) * C_CH);
#pragma unroll
            for (int i = 0; i < 16; ++i) {
                float4 a = row[i], c = row2[i];
                r += a.x * c.x + a.y * c.y + a.z * c.z + a.w * c.w;
                q += a.x * a.x + a.y * a.y + a.z * a.z + a.w * a.w;
            }
        } else {
#pragma unroll
            for (int i = 0; i < 16; ++i) {
                float4 a = row[i];
                q += a.x * a.x + a.y * a.y + a.z * a.z + a.w * a.w;
            }
        }
        r_s[t] = r;
        q_s[t] = q;
    }
    __syncthreads();
    block_scan_4096(r_s, tsum, tid);
    block_scan_4096(q_s, tsum, tid);
    const int nper = T_LEN / p;
    float part = 0.f;
    for (int i = tid; i < nper - 1; i += 256) {
        int s0 = i * p;
        int e = s0 + p;
        int e2 = e + p;
        float crs = s0 ? r_s[s0 - 1] : 0.f;
        float dots = r_s[e - 1] - crs;
        float cqs = s0 ? q_s[s0 - 1] : 0.f;
        float qa = q_s[e - 1] - cqs;
        float qb = q_s[e2 - 1] - q_s[e - 1];
        float na = sqrtf(fmaxf(qa, 0.f));
        float nb = sqrtf(fmaxf(qb, 0.f));
        part += dots / fmaxf(na * nb, 1e-8f);
    }
    tsum[tid] = part;
    __syncthreads();
    for (int off = 128; off > 0; off >>= 1) {
        if (tid < off) tsum[tid] += tsum[tid + off];
        __syncthreads();
    }
    if (tid == 0) scores[b * K2 + cand] = tsum[0] / (float)(nper - 1);
}

// ---------------- K4: final selection + fallback fill ----------------
__global__ void select_kernel(const int* __restrict__ p_int, const int* __restrict__ preval,
                              const float* __restrict__ scores, float* __restrict__ out) {
    const int b = threadIdx.x;
    if (b >= B_N) return;
    int sel[TOPK];
    int cnt = 0;
    for (int j = 0; j < K2; ++j) {
        if (preval[b * K2 + j] && scores[b * K2 + j] > THRESH_V) {
            if (cnt < TOPK) sel[cnt] = p_int[b * K2 + j];
            cnt++;
        }
    }
    if (cnt > TOPK) cnt = TOPK;
    int add[4];
    int nadd = 0;
    int cms[4] = {T_LEN / 4, T_LEN / 3, T_LEN / 2, (int)((float)T_LEN / 1.5f)};
    for (int i = 0; i < 4; ++i)
        if (cms[i] >= 2 && cms[i] <= T_LEN / 2) add[nadd++] = cms[i];
    for (int j = 0; j < TOPK; ++j) {
        float pv, wv;
        if (j < cnt) {
            pv = (float)sel[j];
            wv = 1.0f;
        } else {
            int a = j - cnt;
            if (a > nadd - 1) a = nadd - 1;
            pv = (float)add[a];
            wv = 0.5f;
        }
        out[b * TOPK + j] = pv;
        out[B_N * TOPK + b * TOPK + j] = wv;
    }
}

static size_t align256(size_t v) { return (v + 255) & ~(size_t)255; }

extern "C" void kernel_launch(void* const* d_in, const int* in_sizes, int n_in,
                              void* d_out, int out_size, void* d_ws, size_t ws_size,
                              hipStream_t stream) {
    const float* x = (const float*)d_in[0];
    float* out = (float*)d_out;
    char* ws = (char*)d_ws;

    const size_t amps_b = align256((size_t)B_N * NBINS * sizeof(float));            // ~0.5 MB
    const size_t r_b = align256((size_t)B_N * K2 * T_LEN * sizeof(float));          // 6.3 MB
    const size_t q_b = align256((size_t)B_N * T_LEN * sizeof(float));               // 1 MB
    const size_t int_b = align256((size_t)B_N * K2 * sizeof(int));
    const size_t xbf_b = align256((size_t)B_N * T_LEN * C_CH * sizeof(short));      // 32 MB
    const size_t xt_b = align256((size_t)B_N * T_LEN * C_CH * sizeof(float));       // 64 MB

    size_t off = 0;
    float* amps = (float*)(ws + off); off += amps_b;
    int* p_int = (int*)(ws + off); off += int_b;
    int* preval = (int*)(ws + off); off += int_b;
    float* scores = (float*)(ws + off); off += int_b;
    const size_t small_need = off;
    float* r_ws = (float*)(ws + off); off += r_b;
    float* q_ws = (float*)(ws + off); off += q_b;
    const size_t split_need = off;
    unsigned short* xbf = (unsigned short*)(ws + off); off += xbf_b;
    const size_t bf_need = off;
    float* xt = (float*)(ws + off); off += xt_b;
    const size_t full_need = off;

    hipMemsetAsync(amps, 0, amps_b, stream);

    if (ws_size >= full_need) {
        transpose_cvt_kernel<<<dim3(T_LEN / 64, B_N), 256, 0, stream>>>(x, xt, xbf);
        fft_amp_kernel<true><<<dim3(C_CH / 2, B_N), 256, 0, stream>>>(xt, amps);
        topk_kernel<<<B_N, 256, 0, stream>>>(amps, p_int, preval);
        rq_kernel<<<dim3(T_LEN / 256, B_N), 256, 0, stream>>>(xbf, p_int, r_ws, q_ws);
        score_kernel<<<dim3(K2, B_N), 256, 0, stream>>>(r_ws, q_ws, p_int, scores);
    } else if (ws_size >= bf_need) {
        cvt_kernel<<<2048, 256, 0, stream>>>(x, xbf);
        fft_amp_kernel<false><<<dim3(C_CH / 2, B_N), 256, 0, stream>>>(x, amps);
        topk_kernel<<<B_N, 256, 0, stream>>>(amps, p_int, preval);
        rq_kernel<<<dim3(T_LEN / 256, B_N), 256, 0, stream>>>(xbf, p_int, r_ws, q_ws);
        score_kernel<<<dim3(K2, B_N), 256, 0, stream>>>(r_ws, q_ws, p_int, scores);
    } else {
        fft_amp_kernel<false><<<dim3(C_CH / 2, B_N), 256, 0, stream>>>(x, amps);
        topk_kernel<<<B_N, 256, 0, stream>>>(amps, p_int, preval);
        autocorr_kernel<<<dim3(K2, B_N), 256, 0, stream>>>(x, p_int, scores);
    }
    select_kernel<<<1, 64, 0, stream>>>(p_int, preval, scores, out);
}